// Round 2
// baseline (1051.232 us; speedup 1.0000x reference)
//
#include <hip/hip_runtime.h>

#define N_NODES 50000
#define E_EDGES 800000

// ============================ CSR build =====================================
__global__ __launch_bounds__(256) void k_hist(
    const int* __restrict__ ei, int* __restrict__ cnt)
{
    const int e = blockIdx.x * 256 + threadIdx.x;
    if (e < E_EDGES) atomicAdd(&cnt[ei[E_EDGES + e]], 1);
}

// single block, 1024 threads: exclusive prefix over cnt -> rowptr, cursor
__global__ __launch_bounds__(1024) void k_scan(
    const int* __restrict__ cnt, int* __restrict__ rowptr, int* __restrict__ cursor)
{
    __shared__ int part[1024];
    const int tid = threadIdx.x;
    const int CH = 49;                      // 1024*49 >= 50000
    const int base = tid * CH;
    int sum = 0;
    for (int c = 0; c < CH; ++c) {
        const int i = base + c;
        if (i < N_NODES) sum += cnt[i];
    }
    part[tid] = sum;
    __syncthreads();
    for (int off = 1; off < 1024; off <<= 1) {
        int v = part[tid];
        int u = (tid >= off) ? part[tid - off] : 0;
        __syncthreads();
        part[tid] = v + u;
        __syncthreads();
    }
    int run = (tid > 0) ? part[tid - 1] : 0;
    for (int c = 0; c < CH; ++c) {
        const int i = base + c;
        if (i < N_NODES) {
            rowptr[i] = run;
            cursor[i] = run;
            run += cnt[i];
        }
    }
    if (tid == 1023) rowptr[N_NODES] = part[1023];
}

__global__ __launch_bounds__(256) void k_scatter(
    const int* __restrict__ ei, int* __restrict__ cursor, int2* __restrict__ pairs)
{
    const int e = blockIdx.x * 256 + threadIdx.x;
    if (e < E_EDGES) {
        const int dst = ei[E_EDGES + e];
        const int pos = atomicAdd(&cursor[dst], 1);
        pairs[pos] = make_int2(ei[e], e);
    }
}

// ===================== Edge layer 1 (CSR gather, 16->64) ====================
// out[v][d] = x[v][d] + sum_{e: dst=v} relu( x[src][d] + w_e*(ea_e . We1[d]) + be1[d] )
__global__ __launch_bounds__(256) void k_edge1(
    const int* __restrict__ rp, const int2* __restrict__ pairs,
    const float* __restrict__ eattr, const float* __restrict__ ew,
    const float* __restrict__ We1, const float* __restrict__ be1,
    const float* __restrict__ x, float* __restrict__ out)
{
    const int lane = threadIdx.x & 63;
    const int node = blockIdx.x * 4 + (threadIdx.x >> 6);
    if (node >= N_NODES) return;

    float wr[16];
#pragma unroll
    for (int k = 0; k < 16; ++k) wr[k] = We1[lane * 16 + k];
    const float bias = be1[lane];

    const int beg = rp[node], end = rp[node + 1];
    float acc = 0.f;
    for (int i = beg; i < end; ++i) {
        const int2 se = pairs[i];
        const float w = ew[se.y];
        const float4* ea = (const float4*)(eattr + (size_t)se.y * 16);
        const float4 a0 = ea[0], a1 = ea[1], a2 = ea[2], a3 = ea[3];
        float d0 = fmaf(a0.x, wr[0], a0.y * wr[1]);
        float d1 = fmaf(a0.z, wr[2], a0.w * wr[3]);
        float d2 = fmaf(a1.x, wr[4], a1.y * wr[5]);
        float d3 = fmaf(a1.z, wr[6], a1.w * wr[7]);
        float d4 = fmaf(a2.x, wr[8], a2.y * wr[9]);
        float d5 = fmaf(a2.z, wr[10], a2.w * wr[11]);
        float d6 = fmaf(a3.x, wr[12], a3.y * wr[13]);
        float d7 = fmaf(a3.z, wr[14], a3.w * wr[15]);
        const float dot = ((d0 + d1) + (d2 + d3)) + ((d4 + d5) + (d6 + d7));
        const float m = x[(size_t)se.x * 64 + lane] + fmaf(w, dot, bias);
        acc += fmaxf(m, 0.f);
    }
    out[(size_t)node * 64 + lane] = x[(size_t)node * 64 + lane] + acc;
}

// ===================== Edge layer 2 (CSR gather, 16->128) ===================
__global__ __launch_bounds__(256) void k_edge2(
    const int* __restrict__ rp, const int2* __restrict__ pairs,
    const float* __restrict__ eattr, const float* __restrict__ ew,
    const float* __restrict__ We2, const float* __restrict__ be2,
    const float* __restrict__ h, float* __restrict__ out)
{
    const int lane = threadIdx.x & 63;
    const int node = blockIdx.x * 4 + (threadIdx.x >> 6);
    if (node >= N_NODES) return;

    float wrA[16], wrB[16];
#pragma unroll
    for (int k = 0; k < 16; ++k) wrA[k] = We2[lane * 16 + k];
#pragma unroll
    for (int k = 0; k < 16; ++k) wrB[k] = We2[(lane + 64) * 16 + k];
    const float biasA = be2[lane];
    const float biasB = be2[lane + 64];

    const int beg = rp[node], end = rp[node + 1];
    float accA = 0.f, accB = 0.f;
    for (int i = beg; i < end; ++i) {
        const int2 se = pairs[i];
        const float w = ew[se.y];
        const float4* ea = (const float4*)(eattr + (size_t)se.y * 16);
        const float4 a0 = ea[0], a1 = ea[1], a2 = ea[2], a3 = ea[3];
        float d0 = fmaf(a0.x, wrA[0], a0.y * wrA[1]);
        float d1 = fmaf(a0.z, wrA[2], a0.w * wrA[3]);
        float d2 = fmaf(a1.x, wrA[4], a1.y * wrA[5]);
        float d3 = fmaf(a1.z, wrA[6], a1.w * wrA[7]);
        float d4 = fmaf(a2.x, wrA[8], a2.y * wrA[9]);
        float d5 = fmaf(a2.z, wrA[10], a2.w * wrA[11]);
        float d6 = fmaf(a3.x, wrA[12], a3.y * wrA[13]);
        float d7 = fmaf(a3.z, wrA[14], a3.w * wrA[15]);
        const float dotA = ((d0 + d1) + (d2 + d3)) + ((d4 + d5) + (d6 + d7));
        float e0 = fmaf(a0.x, wrB[0], a0.y * wrB[1]);
        float e1 = fmaf(a0.z, wrB[2], a0.w * wrB[3]);
        float e2 = fmaf(a1.x, wrB[4], a1.y * wrB[5]);
        float e3 = fmaf(a1.z, wrB[6], a1.w * wrB[7]);
        float e4 = fmaf(a2.x, wrB[8], a2.y * wrB[9]);
        float e5 = fmaf(a2.z, wrB[10], a2.w * wrB[11]);
        float e6 = fmaf(a3.x, wrB[12], a3.y * wrB[13]);
        float e7 = fmaf(a3.z, wrB[14], a3.w * wrB[15]);
        const float dotB = ((e0 + e1) + (e2 + e3)) + ((e4 + e5) + (e6 + e7));
        const float mA = h[(size_t)se.x * 128 + lane] + fmaf(w, dotA, biasA);
        const float mB = h[(size_t)se.x * 128 + 64 + lane] + fmaf(w, dotB, biasB);
        accA += fmaxf(mA, 0.f);
        accB += fmaxf(mB, 0.f);
    }
    out[(size_t)node * 128 + lane] = h[(size_t)node * 128 + lane] + accA;
    out[(size_t)node * 128 + 64 + lane] = h[(size_t)node * 128 + 64 + lane] + accB;
}

// ========================= Dense GEMM (node MLP) ============================
// OUT[n][j] = act( sum_k H[n][k]*W[j][k] + b[j] )
// Block 256: nq=tid&7, jq=(tid>>3)&15, half=tid>>7.
// Thread: 8 outputs (j0..j0+7) x 8 nodes (64*half + nq + 8i) -> 64 acc regs.
// LDS: Wt[KIN][128] transposed (conflict-free b128) + hN[NT][KIN+4]
// (b32 banks = (4*nq+k)%32: 8 distinct banks, 2 addrs each -> free).
#define NT 128

template<int KIN, int JOUT, bool RELU>
__global__ __launch_bounds__(256) void k_mlp(
    const float* __restrict__ H, const float* __restrict__ W,
    const float* __restrict__ b, float* __restrict__ OUT)
{
    extern __shared__ float lds[];
    float* Wt = lds;                       // [KIN][128]
    float* hN = Wt + KIN * 128;            // [NT][KIN+4]
    const int HS = KIN + 4;

    const int tid  = threadIdx.x;
    const int nq   = tid & 7;
    const int jq   = (tid >> 3) & 15;
    const int half = tid >> 7;
    const int j0   = jq * 8;

    for (int idx = tid; idx < 128 * KIN; idx += 256) {
        const int j = idx / KIN, k = idx % KIN;
        Wt[k * 128 + j] = (j < JOUT) ? W[idx] : 0.f;
    }
    float bj[8];
#pragma unroll
    for (int m = 0; m < 8; ++m)
        bj[m] = (j0 + m < JOUT) ? b[j0 + m] : 0.f;
    __syncthreads();

    const int base = blockIdx.x * NT;

    for (int idx = tid; idx < NT * (KIN / 4); idx += 256) {
        const int kq = idx & (KIN / 4 - 1);
        const int n  = idx / (KIN / 4);
        const int ng = (base + n < N_NODES) ? (base + n) : (N_NODES - 1);
        *(float4*)(hN + n * HS + 4 * kq) =
            *(const float4*)(H + (size_t)ng * KIN + 4 * kq);
    }
    __syncthreads();

    int hoff[8];
#pragma unroll
    for (int i = 0; i < 8; ++i)
        hoff[i] = (64 * half + nq + 8 * i) * HS;

    float acc[8][8];
#pragma unroll
    for (int i = 0; i < 8; ++i)
#pragma unroll
        for (int m = 0; m < 8; ++m) acc[i][m] = 0.f;

#pragma unroll 4
    for (int k = 0; k < KIN; ++k) {
        const float4 wA = *(const float4*)(Wt + k * 128 + j0);
        const float4 wB = *(const float4*)(Wt + k * 128 + j0 + 4);
        float hv[8];
#pragma unroll
        for (int i = 0; i < 8; ++i) hv[i] = hN[hoff[i] + k];
#pragma unroll
        for (int i = 0; i < 8; ++i) {
            acc[i][0] = fmaf(hv[i], wA.x, acc[i][0]);
            acc[i][1] = fmaf(hv[i], wA.y, acc[i][1]);
            acc[i][2] = fmaf(hv[i], wA.z, acc[i][2]);
            acc[i][3] = fmaf(hv[i], wA.w, acc[i][3]);
            acc[i][4] = fmaf(hv[i], wB.x, acc[i][4]);
            acc[i][5] = fmaf(hv[i], wB.y, acc[i][5]);
            acc[i][6] = fmaf(hv[i], wB.z, acc[i][6]);
            acc[i][7] = fmaf(hv[i], wB.w, acc[i][7]);
        }
    }

#pragma unroll
    for (int i = 0; i < 8; ++i) {
        const int n = base + 64 * half + nq + 8 * i;
        if (n >= N_NODES) continue;
        float v[8];
#pragma unroll
        for (int m = 0; m < 8; ++m) {
            float t = acc[i][m] + bj[m];
            v[m] = RELU ? fmaxf(t, 0.f) : t;
        }
        float* row = OUT + (size_t)n * JOUT;
        if (JOUT == 128) {
            *(float4*)(row + j0)     = make_float4(v[0], v[1], v[2], v[3]);
            *(float4*)(row + j0 + 4) = make_float4(v[4], v[5], v[6], v[7]);
        } else {
#pragma unroll
            for (int m = 0; m < 8; ++m)
                if (j0 + m < JOUT) row[j0 + m] = v[m];
        }
    }
}

// ============================================================================
extern "C" void kernel_launch(void* const* d_in, const int* in_sizes, int n_in,
                              void* d_out, int out_size, void* d_ws, size_t ws_size,
                              hipStream_t stream) {
    const float* x     = (const float*)d_in[0];
    const int*   ei    = (const int*)  d_in[1];
    const float* eattr = (const float*)d_in[2];
    const float* ew    = (const float*)d_in[3];
    const float* We1   = (const float*)d_in[4];
    const float* be1   = (const float*)d_in[5];
    const float* W11   = (const float*)d_in[6];
    const float* b11   = (const float*)d_in[7];
    const float* W12   = (const float*)d_in[8];
    const float* b12   = (const float*)d_in[9];
    const float* We2   = (const float*)d_in[10];
    const float* be2   = (const float*)d_in[11];
    const float* W21   = (const float*)d_in[12];
    const float* b21   = (const float*)d_in[13];
    const float* W22   = (const float*)d_in[14];
    const float* b22   = (const float*)d_in[15];
    const float* Wo    = (const float*)d_in[16];
    const float* bo    = (const float*)d_in[17];
    float* out = (float*)d_out;

    char* ws = (char*)d_ws;
    int*  cnt    = (int*)(ws + 0);            // 200,000 B
    int*  rowptr = (int*)(ws + 204800);       // 200,004 B
    int*  cursor = (int*)(ws + 409600);       // 200,000 B
    int2* pairs  = (int2*)(ws + 614400);      // 6,400,000 B
    float* h1pre = (float*)(ws + 7014400);    // 12.8 MB  (R1)
    float* t1    = (float*)(ws + 19814400);   // 25.6 MB  (R2)
    float* h2pre = t1;                        // R2 reuse (t1 dead)
    float* h2    = t1;                        // R2 reuse (h2pre dead)
    float* h1    = (float*)(ws + 45414400);   // 25.6 MB  (R3)
    float* t2    = h1;                        // R3 reuse (h1 dead)

    hipMemsetAsync(cnt, 0, 200000, stream);

    const int EB = (E_EDGES + 255) / 256;     // 3125
    k_hist<<<EB, 256, 0, stream>>>(ei, cnt);
    k_scan<<<1, 1024, 0, stream>>>(cnt, rowptr, cursor);
    k_scatter<<<EB, 256, 0, stream>>>(ei, cursor, pairs);

    const int NB = (N_NODES + 3) / 4;         // 12500
    k_edge1<<<NB, 256, 0, stream>>>(rowptr, pairs, eattr, ew, We1, be1, x, h1pre);

    const int TILES = (N_NODES + NT - 1) / NT;                       // 391
    const size_t lds64  = (size_t)(64 * 128 + NT * (64 + 4)) * 4;    //  67,584 B
    const size_t lds128 = (size_t)(128 * 128 + NT * (128 + 4)) * 4;  // 133,120 B

    k_mlp<64, 128, true><<<TILES, 256, lds64, stream>>>(h1pre, W11, b11, t1);
    k_mlp<128, 128, true><<<TILES, 256, lds128, stream>>>(t1, W12, b12, h1);

    k_edge2<<<NB, 256, 0, stream>>>(rowptr, pairs, eattr, ew, We2, be2, h1, h2pre);

    k_mlp<128, 128, true><<<TILES, 256, lds128, stream>>>(h2pre, W21, b21, t2);
    k_mlp<128, 128, true><<<TILES, 256, lds128, stream>>>(t2, W22, b22, h2);
    k_mlp<128, 100, false><<<TILES, 256, lds128, stream>>>(h2, Wo, bo, out);
}

// Round 3
// 990.888 us; speedup vs baseline: 1.0609x; 1.0609x over previous
//
#include <hip/hip_runtime.h>

#define N_NODES 50000
#define E_EDGES 800000

// ============================ CSR build =====================================
__global__ __launch_bounds__(256) void k_hist(
    const int* __restrict__ ei, int* __restrict__ cnt)
{
    const int e = blockIdx.x * 256 + threadIdx.x;
    if (e < E_EDGES) atomicAdd(&cnt[ei[E_EDGES + e]], 1);
}

// single block, 1024 threads: exclusive prefix over cnt -> rowptr, cursor
__global__ __launch_bounds__(1024) void k_scan(
    const int* __restrict__ cnt, int* __restrict__ rowptr, int* __restrict__ cursor)
{
    __shared__ int part[1024];
    const int tid = threadIdx.x;
    const int CH = 49;                      // 1024*49 >= 50000
    const int base = tid * CH;
    int sum = 0;
    for (int c = 0; c < CH; ++c) {
        const int i = base + c;
        if (i < N_NODES) sum += cnt[i];
    }
    part[tid] = sum;
    __syncthreads();
    for (int off = 1; off < 1024; off <<= 1) {
        int v = part[tid];
        int u = (tid >= off) ? part[tid - off] : 0;
        __syncthreads();
        part[tid] = v + u;
        __syncthreads();
    }
    int run = (tid > 0) ? part[tid - 1] : 0;
    for (int c = 0; c < CH; ++c) {
        const int i = base + c;
        if (i < N_NODES) {
            rowptr[i] = run;
            cursor[i] = run;
            run += cnt[i];
        }
    }
    if (tid == 1023) rowptr[N_NODES] = part[1023];
}

__global__ __launch_bounds__(256) void k_scatter(
    const int* __restrict__ ei, int* __restrict__ cursor, int2* __restrict__ pairs)
{
    const int e = blockIdx.x * 256 + threadIdx.x;
    if (e < E_EDGES) {
        const int dst = ei[E_EDGES + e];
        const int pos = atomicAdd(&cursor[dst], 1);
        pairs[pos] = make_int2(ei[e], e);
    }
}

// ===================== Edge layer 1 (CSR gather, 16->64) ====================
// out[v][d] = x[v][d] + sum_{e: dst=v} relu( x[src][d] + w_e*(ea_e . We1[d]) + be1[d] )
// One wave per node; lane = dim. Pairs preloaded per 64-edge chunk (coalesced),
// broadcast via __shfl(uniform j) -> readlane; unrolled body keeps 4
// independent gathers in flight.
__global__ __launch_bounds__(256) void k_edge1(
    const int* __restrict__ rp, const int2* __restrict__ pairs,
    const float* __restrict__ eattr, const float* __restrict__ ew,
    const float* __restrict__ We1, const float* __restrict__ be1,
    const float* __restrict__ x, float* __restrict__ out)
{
    const int lane = threadIdx.x & 63;
    const int node = blockIdx.x * 4 + (threadIdx.x >> 6);
    if (node >= N_NODES) return;

    float wr[16];
#pragma unroll
    for (int k = 0; k < 16; ++k) wr[k] = We1[lane * 16 + k];
    const float bias = be1[lane];

    const int beg = rp[node], end = rp[node + 1];
    float acc = 0.f;

    for (int c = beg; c < end; c += 64) {
        const int n = end - c < 64 ? end - c : 64;   // uniform per wave
        const int li = c + (lane < n ? lane : 0);
        const int2  sp = pairs[li];                  // coalesced chunk preload
        const float wp = ew[sp.y];
#pragma unroll 4
        for (int j = 0; j < n; ++j) {
            const int   src = __shfl(sp.x, j);
            const int   eid = __shfl(sp.y, j);
            const float w   = __shfl(wp,  j);
            const float  hv = x[(size_t)src * 64 + lane];
            const float4* ea = (const float4*)(eattr + (size_t)eid * 16);
            const float4 a0 = ea[0], a1 = ea[1], a2 = ea[2], a3 = ea[3];
            float d0 = fmaf(a0.x, wr[0], a0.y * wr[1]);
            float d1 = fmaf(a0.z, wr[2], a0.w * wr[3]);
            float d2 = fmaf(a1.x, wr[4], a1.y * wr[5]);
            float d3 = fmaf(a1.z, wr[6], a1.w * wr[7]);
            float d4 = fmaf(a2.x, wr[8], a2.y * wr[9]);
            float d5 = fmaf(a2.z, wr[10], a2.w * wr[11]);
            float d6 = fmaf(a3.x, wr[12], a3.y * wr[13]);
            float d7 = fmaf(a3.z, wr[14], a3.w * wr[15]);
            const float dot = ((d0 + d1) + (d2 + d3)) + ((d4 + d5) + (d6 + d7));
            acc += fmaxf(hv + fmaf(w, dot, bias), 0.f);
        }
    }
    out[(size_t)node * 64 + lane] = x[(size_t)node * 64 + lane] + acc;
}

// ===================== Edge layer 2 (CSR gather, 16->128) ===================
// Lane owns dims (2*lane, 2*lane+1): h-row gather is one dwordx2 per lane
// (512 B per wave in a single instruction), stores likewise.
__global__ __launch_bounds__(256) void k_edge2(
    const int* __restrict__ rp, const int2* __restrict__ pairs,
    const float* __restrict__ eattr, const float* __restrict__ ew,
    const float* __restrict__ We2, const float* __restrict__ be2,
    const float* __restrict__ h, float* __restrict__ out)
{
    const int lane = threadIdx.x & 63;
    const int node = blockIdx.x * 4 + (threadIdx.x >> 6);
    if (node >= N_NODES) return;

    const int dA = 2 * lane, dB = 2 * lane + 1;
    float wrA[16], wrB[16];
#pragma unroll
    for (int k = 0; k < 16; ++k) wrA[k] = We2[dA * 16 + k];
#pragma unroll
    for (int k = 0; k < 16; ++k) wrB[k] = We2[dB * 16 + k];
    const float biasA = be2[dA];
    const float biasB = be2[dB];

    const int beg = rp[node], end = rp[node + 1];
    float accA = 0.f, accB = 0.f;

    for (int c = beg; c < end; c += 64) {
        const int n = end - c < 64 ? end - c : 64;
        const int li = c + (lane < n ? lane : 0);
        const int2  sp = pairs[li];
        const float wp = ew[sp.y];
#pragma unroll 4
        for (int j = 0; j < n; ++j) {
            const int   src = __shfl(sp.x, j);
            const int   eid = __shfl(sp.y, j);
            const float w   = __shfl(wp,  j);
            const float2 hv = *(const float2*)(h + (size_t)src * 128 + dA);
            const float4* ea = (const float4*)(eattr + (size_t)eid * 16);
            const float4 a0 = ea[0], a1 = ea[1], a2 = ea[2], a3 = ea[3];
            float p0 = fmaf(a0.x, wrA[0], a0.y * wrA[1]);
            float p1 = fmaf(a0.z, wrA[2], a0.w * wrA[3]);
            float p2 = fmaf(a1.x, wrA[4], a1.y * wrA[5]);
            float p3 = fmaf(a1.z, wrA[6], a1.w * wrA[7]);
            float p4 = fmaf(a2.x, wrA[8], a2.y * wrA[9]);
            float p5 = fmaf(a2.z, wrA[10], a2.w * wrA[11]);
            float p6 = fmaf(a3.x, wrA[12], a3.y * wrA[13]);
            float p7 = fmaf(a3.z, wrA[14], a3.w * wrA[15]);
            const float dotA = ((p0 + p1) + (p2 + p3)) + ((p4 + p5) + (p6 + p7));
            float q0 = fmaf(a0.x, wrB[0], a0.y * wrB[1]);
            float q1 = fmaf(a0.z, wrB[2], a0.w * wrB[3]);
            float q2 = fmaf(a1.x, wrB[4], a1.y * wrB[5]);
            float q3 = fmaf(a1.z, wrB[6], a1.w * wrB[7]);
            float q4 = fmaf(a2.x, wrB[8], a2.y * wrB[9]);
            float q5 = fmaf(a2.z, wrB[10], a2.w * wrB[11]);
            float q6 = fmaf(a3.x, wrB[12], a3.y * wrB[13]);
            float q7 = fmaf(a3.z, wrB[14], a3.w * wrB[15]);
            const float dotB = ((q0 + q1) + (q2 + q3)) + ((q4 + q5) + (q6 + q7));
            accA += fmaxf(hv.x + fmaf(w, dotA, biasA), 0.f);
            accB += fmaxf(hv.y + fmaf(w, dotB, biasB), 0.f);
        }
    }
    const float2 self = *(const float2*)(h + (size_t)node * 128 + dA);
    *(float2*)(out + (size_t)node * 128 + dA) =
        make_float2(self.x + accA, self.y + accB);
}

// ========================= Dense GEMM (node MLP) ============================
// OUT[n][j] = act( sum_k H[n][k]*W[j][k] + b[j] )
// Block 256: nq=tid&7, jq=(tid>>3)&15, half=tid>>7.
// Thread: 8 outputs (j0..j0+7) x 8 nodes (64*half + nq + 8i) -> 64 acc regs.
// LDS: Wt[KIN][128] transposed (conflict-free b128) + hN[NT][KIN+4]
// (b32 banks = (4*nq+k)%32: 8 distinct banks, 2 addrs each -> free).
#define NT 128

template<int KIN, int JOUT, bool RELU>
__global__ __launch_bounds__(256) void k_mlp(
    const float* __restrict__ H, const float* __restrict__ W,
    const float* __restrict__ b, float* __restrict__ OUT)
{
    extern __shared__ float lds[];
    float* Wt = lds;                       // [KIN][128]
    float* hN = Wt + KIN * 128;            // [NT][KIN+4]
    const int HS = KIN + 4;

    const int tid  = threadIdx.x;
    const int nq   = tid & 7;
    const int jq   = (tid >> 3) & 15;
    const int half = tid >> 7;
    const int j0   = jq * 8;

    for (int idx = tid; idx < 128 * KIN; idx += 256) {
        const int j = idx / KIN, k = idx % KIN;
        Wt[k * 128 + j] = (j < JOUT) ? W[idx] : 0.f;
    }
    float bj[8];
#pragma unroll
    for (int m = 0; m < 8; ++m)
        bj[m] = (j0 + m < JOUT) ? b[j0 + m] : 0.f;
    __syncthreads();

    const int base = blockIdx.x * NT;

    for (int idx = tid; idx < NT * (KIN / 4); idx += 256) {
        const int kq = idx & (KIN / 4 - 1);
        const int n  = idx / (KIN / 4);
        const int ng = (base + n < N_NODES) ? (base + n) : (N_NODES - 1);
        *(float4*)(hN + n * HS + 4 * kq) =
            *(const float4*)(H + (size_t)ng * KIN + 4 * kq);
    }
    __syncthreads();

    int hoff[8];
#pragma unroll
    for (int i = 0; i < 8; ++i)
        hoff[i] = (64 * half + nq + 8 * i) * HS;

    float acc[8][8];
#pragma unroll
    for (int i = 0; i < 8; ++i)
#pragma unroll
        for (int m = 0; m < 8; ++m) acc[i][m] = 0.f;

#pragma unroll 4
    for (int k = 0; k < KIN; ++k) {
        const float4 wA = *(const float4*)(Wt + k * 128 + j0);
        const float4 wB = *(const float4*)(Wt + k * 128 + j0 + 4);
        float hv[8];
#pragma unroll
        for (int i = 0; i < 8; ++i) hv[i] = hN[hoff[i] + k];
#pragma unroll
        for (int i = 0; i < 8; ++i) {
            acc[i][0] = fmaf(hv[i], wA.x, acc[i][0]);
            acc[i][1] = fmaf(hv[i], wA.y, acc[i][1]);
            acc[i][2] = fmaf(hv[i], wA.z, acc[i][2]);
            acc[i][3] = fmaf(hv[i], wA.w, acc[i][3]);
            acc[i][4] = fmaf(hv[i], wB.x, acc[i][4]);
            acc[i][5] = fmaf(hv[i], wB.y, acc[i][5]);
            acc[i][6] = fmaf(hv[i], wB.z, acc[i][6]);
            acc[i][7] = fmaf(hv[i], wB.w, acc[i][7]);
        }
    }

#pragma unroll
    for (int i = 0; i < 8; ++i) {
        const int n = base + 64 * half + nq + 8 * i;
        if (n >= N_NODES) continue;
        float v[8];
#pragma unroll
        for (int m = 0; m < 8; ++m) {
            float t = acc[i][m] + bj[m];
            v[m] = RELU ? fmaxf(t, 0.f) : t;
        }
        float* row = OUT + (size_t)n * JOUT;
        if (JOUT == 128) {
            *(float4*)(row + j0)     = make_float4(v[0], v[1], v[2], v[3]);
            *(float4*)(row + j0 + 4) = make_float4(v[4], v[5], v[6], v[7]);
        } else {
#pragma unroll
            for (int m = 0; m < 8; ++m)
                if (j0 + m < JOUT) row[j0 + m] = v[m];
        }
    }
}

// ============================================================================
extern "C" void kernel_launch(void* const* d_in, const int* in_sizes, int n_in,
                              void* d_out, int out_size, void* d_ws, size_t ws_size,
                              hipStream_t stream) {
    const float* x     = (const float*)d_in[0];
    const int*   ei    = (const int*)  d_in[1];
    const float* eattr = (const float*)d_in[2];
    const float* ew    = (const float*)d_in[3];
    const float* We1   = (const float*)d_in[4];
    const float* be1   = (const float*)d_in[5];
    const float* W11   = (const float*)d_in[6];
    const float* b11   = (const float*)d_in[7];
    const float* W12   = (const float*)d_in[8];
    const float* b12   = (const float*)d_in[9];
    const float* We2   = (const float*)d_in[10];
    const float* be2   = (const float*)d_in[11];
    const float* W21   = (const float*)d_in[12];
    const float* b21   = (const float*)d_in[13];
    const float* W22   = (const float*)d_in[14];
    const float* b22   = (const float*)d_in[15];
    const float* Wo    = (const float*)d_in[16];
    const float* bo    = (const float*)d_in[17];
    float* out = (float*)d_out;

    char* ws = (char*)d_ws;
    int*  cnt    = (int*)(ws + 0);            // 200,000 B
    int*  rowptr = (int*)(ws + 204800);       // 200,004 B
    int*  cursor = (int*)(ws + 409600);       // 200,000 B
    int2* pairs  = (int2*)(ws + 614400);      // 6,400,000 B
    float* h1pre = (float*)(ws + 7014400);    // 12.8 MB  (R1)
    float* t1    = (float*)(ws + 19814400);   // 25.6 MB  (R2)
    float* h2pre = t1;                        // R2 reuse (t1 dead)
    float* h2    = t1;                        // R2 reuse (h2pre dead)
    float* h1    = (float*)(ws + 45414400);   // 25.6 MB  (R3)
    float* t2    = h1;                        // R3 reuse (h1 dead)

    hipMemsetAsync(cnt, 0, 200000, stream);

    const int EB = (E_EDGES + 255) / 256;     // 3125
    k_hist<<<EB, 256, 0, stream>>>(ei, cnt);
    k_scan<<<1, 1024, 0, stream>>>(cnt, rowptr, cursor);
    k_scatter<<<EB, 256, 0, stream>>>(ei, cursor, pairs);

    const int NB = (N_NODES + 3) / 4;         // 12500
    k_edge1<<<NB, 256, 0, stream>>>(rowptr, pairs, eattr, ew, We1, be1, x, h1pre);

    const int TILES = (N_NODES + NT - 1) / NT;                       // 391
    const size_t lds64  = (size_t)(64 * 128 + NT * (64 + 4)) * 4;    //  67,584 B
    const size_t lds128 = (size_t)(128 * 128 + NT * (128 + 4)) * 4;  // 133,120 B

    k_mlp<64, 128, true><<<TILES, 256, lds64, stream>>>(h1pre, W11, b11, t1);
    k_mlp<128, 128, true><<<TILES, 256, lds128, stream>>>(t1, W12, b12, h1);

    k_edge2<<<NB, 256, 0, stream>>>(rowptr, pairs, eattr, ew, We2, be2, h1, h2pre);

    k_mlp<128, 128, true><<<TILES, 256, lds128, stream>>>(h2pre, W21, b21, t2);
    k_mlp<128, 128, true><<<TILES, 256, lds128, stream>>>(t2, W22, b22, h2);
    k_mlp<128, 100, false><<<TILES, 256, lds128, stream>>>(h2, Wo, bo, out);
}